// Round 4
// baseline (243.486 us; speedup 1.0000x reference)
//
#include <hip/hip_runtime.h>
#include <stdint.h>
#include <stddef.h>

// B=32, S=1024, E=768, HD=64, NIP=49.  out = softmax(mask(QK^T/8)) @ V.
// k0: Wt[192][768] bf16 (contiguous W reads, strided L2 writes) +
//     padneg[32][1024] f32 (pad ? -16384 : 0)
// k1: QKV proj, NO LDS / NO BARRIERS: each wave = independent 16-row strip,
//     X direct global->reg A-frags (2-stage prefetch), W B-frags direct
//     from global (L1/L2 broadcast across the 8 co-resident waves; address
//     equivalence-checked vs the verified LDS version). 12 f32x4 acc.
//     V written transposed Vt[b][d][s]; Q pre-scaled by 1/8*log2(e).
// k2: flash attn, BM=64, BN=128, SWAPPED QK^T (mfma(K,Q)) so P lives
//     per-query in registers; P->bf16 A-frags via v_cvt_pk_bf16_f32 +
//     permlane32/16_swap butterfly (no LDS P strip); pad mask folded into
//     QK^T accumulator init via padneg; fixed-max softmax, row-sum via
//     ones-tile MFMA, K/V via global_load_lds 1-tile-ahead prefetch, LPT.

typedef __attribute__((ext_vector_type(8))) short bf16x8;
typedef __attribute__((ext_vector_type(4))) float f32x4;

#define NIP 49
#define QSCALE 0.18033688011112042f /* 0.125 * log2(e) */

#define GLDS16(g, l)                                      \
  __builtin_amdgcn_global_load_lds(                       \
      (const __attribute__((address_space(1))) void*)(g), \
      (__attribute__((address_space(3))) void*)(l), 16, 0, 0)

__device__ __forceinline__ short f2b(float f) {
  union { float f; uint32_t u; } c; c.f = f;
  uint32_t u = c.u;
  uint32_t r = (u + 0x7fffu + ((u >> 16) & 1u)) >> 16;  // RNE
  return (short)(uint16_t)r;
}

// pack two f32 -> two bf16 (RNE) in one VALU op; lo -> bits[15:0]
__device__ __forceinline__ uint32_t pk2(float lo, float hi) {
  uint32_t r;
  asm("v_cvt_pk_bf16_f32 %0, %1, %2" : "=v"(r) : "v"(lo), "v"(hi));
  return r;
}

// ---------------- kernel 0: W -> Wt bf16 [192][768]; padneg ----------------
// Contiguous reads of W (coalesced); strided 2B writes land in L2 (Wt is
// 288 KB, L2-resident) and merge before writeback.
__global__ __launch_bounds__(256) void wt_kernel(
    const float* __restrict__ Wq, const float* __restrict__ Wk,
    const float* __restrict__ Wv, const int* __restrict__ pad,
    short* __restrict__ Wt, float* __restrict__ padneg) {
  int idx = blockIdx.x * 256 + threadIdx.x;  // 0..147455
  int m = idx / 49152;                       // which matrix
  int idx2 = idx - m * 49152;                // k*64 + n
  int k = idx2 >> 6, n = idx2 & 63;
  const float* W = (m == 0) ? Wq : (m == 1) ? Wk : Wv;
  Wt[(size_t)(m * 64 + n) * 768 + k] = f2b(W[idx2]);
  if (idx < 32768) padneg[idx] = pad[idx] ? -16384.f : 0.f;
}

// ---------------- kernel 1: QKV projection (no LDS, no barriers) ----------
// 512 blocks x 256 threads; each wave independently computes 16 rows x 192.
__global__ __launch_bounds__(256) void proj_kernel(
    const float* __restrict__ X, const float* __restrict__ bq,
    const float* __restrict__ bk, const float* __restrict__ bv,
    const short* __restrict__ Wt, short* __restrict__ Qg,
    short* __restrict__ Kg, short* __restrict__ Vt) {
  const int tid = threadIdx.x;
  const int wid = tid >> 6, lane = tid & 63;
  const int l15 = lane & 15, q4 = lane >> 4;
  const int r0 = blockIdx.x * 64;

  // X: this lane's A-frag source row; 4 float4/stage, 2-stage reg prefetch
  const float* xrow = X + (size_t)(r0 + wid * 16 + l15) * 768;
  float4 xa[2][4];
  auto xload = [&](int slot, int st) {
    const int kb = st * 64 + q4 * 8;
#pragma unroll
    for (int h = 0; h < 2; ++h) {
      xa[slot][h * 2 + 0] = *(const float4*)(xrow + kb + h * 32);
      xa[slot][h * 2 + 1] = *(const float4*)(xrow + kb + h * 32 + 4);
    }
  };
  auto mkfrag = [&](int slot, int h) {
    union { uint32_t u[4]; bf16x8 v; } r;
    const float4 a = xa[slot][h * 2], b = xa[slot][h * 2 + 1];
    r.u[0] = pk2(a.x, a.y); r.u[1] = pk2(a.z, a.w);
    r.u[2] = pk2(b.x, b.y); r.u[3] = pk2(b.z, b.w);
    return r.v;
  };

  // W B-frag base: lane reads Wt[(c*16+l15)*768 + st*64 + ks*32 + q4*8].
  // 16 B/lane, 16 full cache lines per instruction; L1/L2-served
  // (all co-resident waves walk the same 288 KB Wt).
  const short* wrow = Wt + (size_t)l15 * 768 + q4 * 8;

  f32x4 acc[12];
#pragma unroll
  for (int c = 0; c < 12; ++c) acc[c] = (f32x4){0.f, 0.f, 0.f, 0.f};

  xload(0, 0);
  xload(1, 1);

#pragma unroll
  for (int st = 0; st < 12; ++st) {
    const int cur = st & 1;
    const bf16x8 a0 = mkfrag(cur, 0);
    const bf16x8 a1 = mkfrag(cur, 1);
    if (st + 2 < 12) xload(cur, st + 2);
#pragma unroll
    for (int c = 0; c < 12; ++c) {
      const short* wp = wrow + (size_t)c * 12288 + st * 64;
      const bf16x8 b0 = *(const bf16x8*)(wp);
      const bf16x8 b1 = *(const bf16x8*)(wp + 32);
      acc[c] = __builtin_amdgcn_mfma_f32_16x16x32_bf16(a0, b0, acc[c], 0, 0, 0);
      acc[c] = __builtin_amdgcn_mfma_f32_16x16x32_bf16(a1, b1, acc[c], 0, 0, 0);
    }
  }

  // epilogue: C/D col=l15, row=q4*4+rr
  const int b = r0 >> 10, s0 = r0 & 1023;
#pragma unroll
  for (int c = 0; c < 12; ++c) {
    const int mtx = c >> 2;
    const int h = (c & 3) * 16 + l15;
    if (mtx < 2) {
      const float bias = (mtx == 0 ? bq : bk)[h];
      short* op = (mtx == 0) ? Qg : Kg;
#pragma unroll
      for (int rr = 0; rr < 4; ++rr) {
        int row = r0 + wid * 16 + q4 * 4 + rr;
        float v = acc[c][rr] + bias;
        if (mtx == 0) v *= QSCALE;
        op[(size_t)row * 64 + h] = f2b(v);
      }
    } else {
      const float bias = bv[h];
      uint2 sv;
      sv.x = pk2(acc[c][0] + bias, acc[c][1] + bias);
      sv.y = pk2(acc[c][2] + bias, acc[c][3] + bias);
      *(uint2*)(Vt + ((size_t)(b * 64 + h) << 10) + s0 + wid * 16 + q4 * 4) = sv;
    }
  }
}

// ---------------- kernel 2: flash attention, BN=128, swapped QK^T ----------
// grid (32 batches fast, 16 levels); level 0 -> t=0, level L -> t=16-L (LPT).
__global__ __launch_bounds__(256, 2) void attn_kernel(
    const short* __restrict__ Qg, const short* __restrict__ Kg,
    const short* __restrict__ Vt, const float* __restrict__ padneg,
    float* __restrict__ out) {
  __shared__ short lK[2][2][128][32];  // [buf][dhalf][key][d32]  32 KB
  __shared__ short lV[2][4][64][32];   // [buf][kq][d][key32]     32 KB
  __shared__ short lOnes[16][32];      // ones B-tile (row0=1.0)  1 KB

  const int b = blockIdx.x;
  const int level = blockIdx.y;
  const int t = (level == 0) ? 0 : 16 - level;
  const int tid = threadIdx.x;
  const int wid = tid >> 6, lane = tid & 63;
  const int l15 = lane & 15, q4 = lane >> 4;
  const int qs = t * 64;
  const size_t base = (size_t)b * 1024;
  const int nkt = (t == 0) ? 8 : (t / 2 + 1);

  {  // init ones tile: 512 shorts
    int i0 = tid, i1 = tid + 256;
    ((short*)lOnes)[i0] = ((i0 >> 5) == 0) ? (short)0x3F80 : (short)0;
    if (i1 < 512) ((short*)lOnes)[i1] = ((i1 >> 5) == 0) ? (short)0x3F80 : (short)0;
  }

  // Q B-frags straight from global (lane row = query = qs + wid*16 + l15)
  const short* qrow = Qg + (base + qs + wid * 16 + l15) * 64;
  bf16x8 bq0 = *(const bf16x8*)(qrow + q4 * 8);
  bf16x8 bq1 = *(const bf16x8*)(qrow + 32 + q4 * 8);
  const int qi = qs + wid * 16 + l15;  // this lane's query row

  const int sr = lane >> 2, sc = (lane & 3) * 8;
  auto wlds_tile = [&](int buf, int kt) {
    const int kb = kt * 128;
    // K: 128 keys x 64 d; wave wid covers key quarter wid*32
#pragma unroll
    for (int i = 0; i < 4; ++i) {
      const int dh = i & 1, krow = wid * 32 + (i >> 1) * 16;
      GLDS16(Kg + (base + kb + krow + sr) * 64 + dh * 32 + sc,
             &lK[buf][dh][krow][0]);
    }
    // V: 64 d x 128 keys from Vt[b][d][s]; wave wid covers d strip wid*16
#pragma unroll
    for (int kq = 0; kq < 4; ++kq) {
      GLDS16(Vt + ((size_t)(b * 64 + wid * 16 + sr) << 10) + kb + kq * 32 + sc,
             &lV[buf][kq][wid * 16][0]);
    }
  };

  // padneg for this lane's keys: key = kb + c*16 + q4*4 + rr  -> float4
  float4 pnv[8];
  auto pnload = [&](int kt) {
#pragma unroll
    for (int c = 0; c < 8; ++c)
      pnv[c] = *(const float4*)(padneg + base + kt * 128 + c * 16 + q4 * 4);
  };

  pnload(0);
  wlds_tile(0, 0);
  __syncthreads();

  f32x4 o[5];  // o[4] = row-sum l via ones tile
#pragma unroll
  for (int c = 0; c < 5; ++c) o[c] = (f32x4){0.f, 0.f, 0.f, 0.f};

  for (int kt = 0; kt < nkt; ++kt) {
    const int cur = kt & 1;
    const int kb = kt * 128;

    // S^T = K Q^T: accumulator pre-loaded with padneg (pad mask is free)
    f32x4 s4[8];
#pragma unroll
    for (int c = 0; c < 8; ++c)
      s4[c] = (f32x4){pnv[c].x, pnv[c].y, pnv[c].z, pnv[c].w};

    if (kt + 1 < nkt) {
      wlds_tile(cur ^ 1, kt + 1);  // in flight until body-end barrier
      pnload(kt + 1);              // pnv already consumed into s4
    }

    // swapped QK^T: D row (q4*4+rr) = key, col (l15) = query
#pragma unroll
    for (int c = 0; c < 8; ++c) {
      bf16x8 a0 = *(const bf16x8*)&lK[cur][0][c * 16 + l15][q4 * 8];
      s4[c] = __builtin_amdgcn_mfma_f32_16x16x32_bf16(a0, bq0, s4[c], 0, 0, 0);
      bf16x8 a1 = *(const bf16x8*)&lK[cur][1][c * 16 + l15][q4 * 8];
      s4[c] = __builtin_amdgcn_mfma_f32_16x16x32_bf16(a1, bq1, s4[c], 0, 0, 0);
    }

    // fixed-max softmax in place: p = exp2(min(s,80)); causal/img masks
    const bool diag = (t == 0) ? (kt == 0) : (kt == nkt - 1);
    const bool img = (t == 0 && kt > 0);
#pragma unroll
    for (int c = 0; c < 8; ++c) {
#pragma unroll
      for (int rr = 0; rr < 4; ++rr) {
        float pv = exp2f(fminf(s4[c][rr], 80.f));
        if (diag) {
          int j = kb + c * 16 + q4 * 4 + rr;
          if (qi >= NIP && j > qi) pv = 0.f;
        }
        if (img) {
          if (qi >= NIP) pv = 0.f;
        }
        s4[c][rr] = pv;
      }
    }

    // PV: per 32-key block, assemble bf16 A-frag fully in registers.
    // w0..w3 = cvt_pk key-pairs; (X0,X2)=permlane16(permlane32(w0,w2)),
    // (X1,X3)= same on (w1,w3).  A-frag keys = q4*8 + 0..7.
#pragma unroll
    for (int m = 0; m < 4; ++m) {
      uint32_t w0 = pk2(s4[2 * m][0], s4[2 * m][1]);
      uint32_t w1 = pk2(s4[2 * m][2], s4[2 * m][3]);
      uint32_t w2 = pk2(s4[2 * m + 1][0], s4[2 * m + 1][1]);
      uint32_t w3 = pk2(s4[2 * m + 1][2], s4[2 * m + 1][3]);
      asm("v_permlane32_swap_b32 %0, %1" : "+v"(w0), "+v"(w2));
      asm("v_permlane32_swap_b32 %0, %1" : "+v"(w1), "+v"(w3));
      asm("v_permlane16_swap_b32 %0, %1" : "+v"(w0), "+v"(w2));
      asm("v_permlane16_swap_b32 %0, %1" : "+v"(w1), "+v"(w3));
      union { uint32_t u[4]; bf16x8 v; } af;
      af.u[0] = w0; af.u[1] = w1; af.u[2] = w2; af.u[3] = w3;
#pragma unroll
      for (int c = 0; c < 5; ++c) {
        bf16x8 bv = (c < 4) ? *(const bf16x8*)&lV[cur][m][c * 16 + l15][q4 * 8]
                            : *(const bf16x8*)&lOnes[l15][q4 * 8];
        o[c] = __builtin_amdgcn_mfma_f32_16x16x32_bf16(af.v, bv, o[c], 0, 0, 0);
      }
    }
    __syncthreads();
  }

#pragma unroll
  for (int rr = 0; rr < 4; ++rr) {
    float l = __shfl(o[4][rr], lane & 48, 64);  // col 0 of this quad
    const float inv = (l > 0.f) ? 1.0f / l : 0.f;
    const size_t row = base + qs + wid * 16 + q4 * 4 + rr;
#pragma unroll
    for (int c = 0; c < 4; ++c)
      out[row * 64 + c * 16 + l15] = o[c][rr] * inv;
  }
}

extern "C" void kernel_launch(void* const* d_in, const int* in_sizes, int n_in,
                              void* d_out, int out_size, void* d_ws, size_t ws_size,
                              hipStream_t stream) {
  const float* X  = (const float*)d_in[0];
  const float* Wq = (const float*)d_in[1];
  const float* bq = (const float*)d_in[2];
  const float* Wk = (const float*)d_in[3];
  const float* bk = (const float*)d_in[4];
  const float* Wv = (const float*)d_in[5];
  const float* bv = (const float*)d_in[6];
  const int* pad  = (const int*)d_in[8];
  float* out = (float*)d_out;

  short* Qg = (short*)d_ws;              // 4 MB
  short* Kg = Qg + 32768 * 64;           // 4 MB
  short* Vt = Kg + 32768 * 64;           // 4 MB, [32][64][1024]
  short* Wt = Vt + 32768 * 64;           // 288 KB
  float* padneg = (float*)(Wt + 147456); // 128 KB

  wt_kernel<<<576, 256, 0, stream>>>(Wq, Wk, Wv, pad, Wt, padneg);
  proj_kernel<<<512, 256, 0, stream>>>(X, bq, bk, bv, Wt, Qg, Kg, Vt);
  attn_kernel<<<dim3(32, 16), 256, 0, stream>>>(Qg, Kg, Vt, padneg, out);
}

// Round 7
// 197.985 us; speedup vs baseline: 1.2298x; 1.2298x over previous
//
#include <hip/hip_runtime.h>
#include <stdint.h>
#include <stddef.h>

// B=32, S=1024, E=768, HD=64, NIP=49.  out = softmax(mask(QK^T/8)) @ V.
// k0: Wt staged-order bf16 [st][ks][192][32] (XOR bank-swizzle baked in;
//     coalesced W reads)  +  padneg[32][1024] f32 (pad ? -16384 : 0)
// k1: QKV proj, 256 thr, BK=64. W staging is CONTIGUOUS 24 KB/stage
//     (24 x 1KB fully-used-line glds, PER-LANE src = base + lane*16B —
//     global_load_lds source must be per-lane, m104/m173; R6's bug was a
//     wave-uniform src).  X direct global->reg A-frags, 2-stage prefetch,
//     counted s_waitcnt vmcnt(4) + raw s_barrier, glds order pinned with
//     sched_barrier(0) (rule #18).
//     V written transposed Vt[b][d][s]; Q pre-scaled by 1/8*log2(e).
// k2: flash attn, BM=64, BN=128, SWAPPED QK^T (mfma(K,Q)) so P lives
//     per-query in registers; P->bf16 A-frags via v_cvt_pk_bf16_f32 +
//     permlane32/16_swap butterfly (no LDS P strip); pad mask folded into
//     QK^T accumulator init via padneg; fixed-max softmax, row-sum via
//     ones-tile MFMA, K/V via global_load_lds 1-tile-ahead prefetch, LPT.

typedef __attribute__((ext_vector_type(8))) short bf16x8;
typedef __attribute__((ext_vector_type(4))) float f32x4;

#define NIP 49
#define QSCALE 0.18033688011112042f /* 0.125 * log2(e) */

#define GLDS16(g, l)                                      \
  __builtin_amdgcn_global_load_lds(                       \
      (const __attribute__((address_space(1))) void*)(g), \
      (__attribute__((address_space(3))) void*)(l), 16, 0, 0)

__device__ __forceinline__ short f2b(float f) {
  union { float f; uint32_t u; } c; c.f = f;
  uint32_t u = c.u;
  uint32_t r = (u + 0x7fffu + ((u >> 16) & 1u)) >> 16;  // RNE
  return (short)(uint16_t)r;
}

// pack two f32 -> two bf16 (RNE) in one VALU op; lo -> bits[15:0]
__device__ __forceinline__ uint32_t pk2(float lo, float hi) {
  uint32_t r;
  asm("v_cvt_pk_bf16_f32 %0, %1, %2" : "=v"(r) : "v"(lo), "v"(hi));
  return r;
}

// ---------------- kernel 0: W -> staged Wt; padneg ----------------
// Wt short-index = st*12288 + ks*6144 + n*32 + t*8 + b  holds
// W[k][n] with k = st*64 + ks*32 + (t ^ ((n>>1)&3))*8 + b.
// One thread per SOURCE element -> fully coalesced reads; scattered 2B
// writes land in L2 (Wt is 288 KB, L2-resident) and merge.
__global__ __launch_bounds__(256) void wt_kernel(
    const float* __restrict__ Wq, const float* __restrict__ Wk,
    const float* __restrict__ Wv, const int* __restrict__ pad,
    short* __restrict__ Wt, float* __restrict__ padneg) {
  int e = blockIdx.x * 256 + threadIdx.x;  // 0..147455
  int m = e / 49152;
  int r = e - m * 49152;  // k*64 + n_loc
  int k = r >> 6, nl = r & 63;
  int n = m * 64 + nl;
  const float* W = (m == 0) ? Wq : (m == 1) ? Wk : Wv;
  const float v = W[r];
  int st = k >> 6, k64 = k & 63;
  int ks = k64 >> 5, k32 = k64 & 31;
  int t = (k32 >> 3) ^ ((n >> 1) & 3), b = k32 & 7;
  Wt[st * 12288 + ks * 6144 + n * 32 + t * 8 + b] = f2b(v);
  if (e < 32768) padneg[e] = pad[e] ? -16384.f : 0.f;
}

// ---------------- kernel 1: QKV projection ----------------
// 512 blocks x 256 threads (4 waves = 4 row strips; each wave all 12 ctiles).
__global__ __launch_bounds__(256, 3) void proj_kernel(
    const float* __restrict__ X, const float* __restrict__ bq,
    const float* __restrict__ bk, const float* __restrict__ bv,
    const short* __restrict__ Wt, short* __restrict__ Qg,
    short* __restrict__ Kg, short* __restrict__ Vt) {
  __shared__ short lW[2][2][192][32];  // [buf][khalf][n][k-swz] 48 KB
  const int tid = threadIdx.x;
  const int wid = tid >> 6, lane = tid & 63;
  const int l15 = lane & 15, q4 = lane >> 4;
  const int r0 = blockIdx.x * 64;
  const int sig = (l15 >> 1) & 3;  // read-side swizzle sigma(row mod 16)

  // X: this lane's A-frag source row; 4 float4/stage, 2-stage reg prefetch
  const float* xrow = X + (size_t)(r0 + wid * 16 + l15) * 768;
  float4 xa[2][4];
  auto xload = [&](int slot, int st) {
    const int kb = st * 64 + q4 * 8;
#pragma unroll
    for (int h = 0; h < 2; ++h) {
      xa[slot][h * 2 + 0] = *(const float4*)(xrow + kb + h * 32);
      xa[slot][h * 2 + 1] = *(const float4*)(xrow + kb + h * 32 + 4);
    }
  };
  auto mkfrag = [&](int slot, int h) {
    union { uint32_t u[4]; bf16x8 v; } r;
    const float4 a = xa[slot][h * 2], b = xa[slot][h * 2 + 1];
    r.u[0] = pk2(a.x, a.y); r.u[1] = pk2(a.z, a.w);
    r.u[2] = pk2(b.x, b.y); r.u[3] = pk2(b.z, b.w);
    return r.v;
  };

  // W: 24 KB/stage, fully CONTIGUOUS in staged Wt: 24 x 1KB glds, 6/wave.
  // Per-lane global src (base + lane*16B); LDS dest = uniform base +
  // lane*16B (hardware). Linear 1KB copy per glds.
  auto wlds = [&](int buf, int st) {
    const short* src = Wt + (size_t)st * 12288 + lane * 8;
    short* dst = &lW[buf][0][0][0];
#pragma unroll
    for (int i = 0; i < 6; ++i) {
      const int g = wid * 6 + i;  // 0..23 -> byte offset g*1024
      GLDS16(src + g * 512, dst + g * 512);
    }
  };

  f32x4 acc[12];
#pragma unroll
  for (int c = 0; c < 12; ++c) acc[c] = (f32x4){0.f, 0.f, 0.f, 0.f};

  // prologue: glds first (older), PINNED; then 8 X loads; drain the glds.
  wlds(0, 0);
  __builtin_amdgcn_sched_barrier(0);  // glds stay oldest (rule #18)
  xload(0, 0);
  xload(1, 1);
  asm volatile("s_waitcnt vmcnt(8) lgkmcnt(0)" ::: "memory");
  __builtin_amdgcn_s_barrier();

#pragma unroll
  for (int st = 0; st < 12; ++st) {
    const int cur = st & 1;
    if (st + 1 < 12) {
      wlds(cur ^ 1, st + 1);  // 24 glds: must be the oldest vmem this body
      __builtin_amdgcn_sched_barrier(0);  // pin issue order (rule #18)
    }
    const bf16x8 a0 = mkfrag(cur, 0);
    const bf16x8 a1 = mkfrag(cur, 1);
    if (st + 2 < 12) xload(cur, st + 2);  // 4 reg loads (youngest)
#pragma unroll
    for (int ks = 0; ks < 2; ++ks) {
      const bf16x8 a = ks ? a1 : a0;
#pragma unroll
      for (int c = 0; c < 12; ++c) {
        const bf16x8 bw =
            *(const bf16x8*)&lW[cur][ks][c * 16 + l15][(q4 ^ sig) * 8];
        acc[c] = __builtin_amdgcn_mfma_f32_16x16x32_bf16(a, bw, acc[c], 0, 0, 0);
      }
    }
    // counted drain: glds for st+1 complete; the 4 X loads for st+2 stay
    // in flight across the barrier.
    if (st + 2 < 12)
      asm volatile("s_waitcnt vmcnt(4) lgkmcnt(0)" ::: "memory");
    else
      asm volatile("s_waitcnt vmcnt(0) lgkmcnt(0)" ::: "memory");
    __builtin_amdgcn_s_barrier();
  }

  // epilogue: C/D col=l15, row=q4*4+rr
  const int b = r0 >> 10, s0 = r0 & 1023;
#pragma unroll
  for (int c = 0; c < 12; ++c) {
    const int mtx = c >> 2;
    const int h = (c & 3) * 16 + l15;
    if (mtx < 2) {
      const float bias = (mtx == 0 ? bq : bk)[h];
      short* op = (mtx == 0) ? Qg : Kg;
#pragma unroll
      for (int rr = 0; rr < 4; ++rr) {
        int row = r0 + wid * 16 + q4 * 4 + rr;
        float v = acc[c][rr] + bias;
        if (mtx == 0) v *= QSCALE;
        op[(size_t)row * 64 + h] = f2b(v);
      }
    } else {
      const float bias = bv[h];
      uint2 sv;
      sv.x = pk2(acc[c][0] + bias, acc[c][1] + bias);
      sv.y = pk2(acc[c][2] + bias, acc[c][3] + bias);
      *(uint2*)(Vt + ((size_t)(b * 64 + h) << 10) + s0 + wid * 16 + q4 * 4) = sv;
    }
  }
}

// ---------------- kernel 2: flash attention, BN=128, swapped QK^T ----------
// grid (32 batches fast, 16 levels); level 0 -> t=0, level L -> t=16-L (LPT).
__global__ __launch_bounds__(256, 2) void attn_kernel(
    const short* __restrict__ Qg, const short* __restrict__ Kg,
    const short* __restrict__ Vt, const float* __restrict__ padneg,
    float* __restrict__ out) {
  __shared__ short lK[2][2][128][32];  // [buf][dhalf][key][d32]  32 KB
  __shared__ short lV[2][4][64][32];   // [buf][kq][d][key32]     32 KB
  __shared__ short lOnes[16][32];      // ones B-tile (row0=1.0)  1 KB

  const int b = blockIdx.x;
  const int level = blockIdx.y;
  const int t = (level == 0) ? 0 : 16 - level;
  const int tid = threadIdx.x;
  const int wid = tid >> 6, lane = tid & 63;
  const int l15 = lane & 15, q4 = lane >> 4;
  const int qs = t * 64;
  const size_t base = (size_t)b * 1024;
  const int nkt = (t == 0) ? 8 : (t / 2 + 1);

  {  // init ones tile: 512 shorts
    int i0 = tid, i1 = tid + 256;
    ((short*)lOnes)[i0] = ((i0 >> 5) == 0) ? (short)0x3F80 : (short)0;
    if (i1 < 512) ((short*)lOnes)[i1] = ((i1 >> 5) == 0) ? (short)0x3F80 : (short)0;
  }

  // Q B-frags straight from global (lane row = query = qs + wid*16 + l15)
  const short* qrow = Qg + (base + qs + wid * 16 + l15) * 64;
  bf16x8 bq0 = *(const bf16x8*)(qrow + q4 * 8);
  bf16x8 bq1 = *(const bf16x8*)(qrow + 32 + q4 * 8);
  const int qi = qs + wid * 16 + l15;  // this lane's query row

  const int sr = lane >> 2, sc = (lane & 3) * 8;
  auto wlds_tile = [&](int buf, int kt) {
    const int kb = kt * 128;
    // K: 128 keys x 64 d; wave wid covers key quarter wid*32
#pragma unroll
    for (int i = 0; i < 4; ++i) {
      const int dh = i & 1, krow = wid * 32 + (i >> 1) * 16;
      GLDS16(Kg + (base + kb + krow + sr) * 64 + dh * 32 + sc,
             &lK[buf][dh][krow][0]);
    }
    // V: 64 d x 128 keys from Vt[b][d][s]; wave wid covers d strip wid*16
#pragma unroll
    for (int kq = 0; kq < 4; ++kq) {
      GLDS16(Vt + ((size_t)(b * 64 + wid * 16 + sr) << 10) + kb + kq * 32 + sc,
             &lV[buf][kq][wid * 16][0]);
    }
  };

  // padneg for this lane's keys: key = kb + c*16 + q4*4 + rr  -> float4
  float4 pnv[8];
  auto pnload = [&](int kt) {
#pragma unroll
    for (int c = 0; c < 8; ++c)
      pnv[c] = *(const float4*)(padneg + base + kt * 128 + c * 16 + q4 * 4);
  };

  pnload(0);
  wlds_tile(0, 0);
  __syncthreads();

  f32x4 o[5];  // o[4] = row-sum l via ones tile
#pragma unroll
  for (int c = 0; c < 5; ++c) o[c] = (f32x4){0.f, 0.f, 0.f, 0.f};

  for (int kt = 0; kt < nkt; ++kt) {
    const int cur = kt & 1;
    const int kb = kt * 128;

    // S^T = K Q^T: accumulator pre-loaded with padneg (pad mask is free)
    f32x4 s4[8];
#pragma unroll
    for (int c = 0; c < 8; ++c)
      s4[c] = (f32x4){pnv[c].x, pnv[c].y, pnv[c].z, pnv[c].w};

    if (kt + 1 < nkt) {
      wlds_tile(cur ^ 1, kt + 1);  // in flight until body-end barrier
      pnload(kt + 1);              // pnv already consumed into s4
    }

    // swapped QK^T: D row (q4*4+rr) = key, col (l15) = query
#pragma unroll
    for (int c = 0; c < 8; ++c) {
      bf16x8 a0 = *(const bf16x8*)&lK[cur][0][c * 16 + l15][q4 * 8];
      s4[c] = __builtin_amdgcn_mfma_f32_16x16x32_bf16(a0, bq0, s4[c], 0, 0, 0);
      bf16x8 a1 = *(const bf16x8*)&lK[cur][1][c * 16 + l15][q4 * 8];
      s4[c] = __builtin_amdgcn_mfma_f32_16x16x32_bf16(a1, bq1, s4[c], 0, 0, 0);
    }

    // fixed-max softmax in place: p = exp2(min(s,80)); causal/img masks
    const bool diag = (t == 0) ? (kt == 0) : (kt == nkt - 1);
    const bool img = (t == 0 && kt > 0);
#pragma unroll
    for (int c = 0; c < 8; ++c) {
#pragma unroll
      for (int rr = 0; rr < 4; ++rr) {
        float pv = exp2f(fminf(s4[c][rr], 80.f));
        if (diag) {
          int j = kb + c * 16 + q4 * 4 + rr;
          if (qi >= NIP && j > qi) pv = 0.f;
        }
        if (img) {
          if (qi >= NIP) pv = 0.f;
        }
        s4[c][rr] = pv;
      }
    }

    // PV: per 32-key block, assemble bf16 A-frag fully in registers.
    // w0..w3 = cvt_pk key-pairs; (X0,X2)=permlane16(permlane32(w0,w2)),
    // (X1,X3)= same on (w1,w3).  A-frag keys = q4*8 + 0..7.
#pragma unroll
    for (int m = 0; m < 4; ++m) {
      uint32_t w0 = pk2(s4[2 * m][0], s4[2 * m][1]);
      uint32_t w1 = pk2(s4[2 * m][2], s4[2 * m][3]);
      uint32_t w2 = pk2(s4[2 * m + 1][0], s4[2 * m + 1][1]);
      uint32_t w3 = pk2(s4[2 * m + 1][2], s4[2 * m + 1][3]);
      asm("v_permlane32_swap_b32 %0, %1" : "+v"(w0), "+v"(w2));
      asm("v_permlane32_swap_b32 %0, %1" : "+v"(w1), "+v"(w3));
      asm("v_permlane16_swap_b32 %0, %1" : "+v"(w0), "+v"(w2));
      asm("v_permlane16_swap_b32 %0, %1" : "+v"(w1), "+v"(w3));
      union { uint32_t u[4]; bf16x8 v; } af;
      af.u[0] = w0; af.u[1] = w1; af.u[2] = w2; af.u[3] = w3;
#pragma unroll
      for (int c = 0; c < 5; ++c) {
        bf16x8 bv = (c < 4) ? *(const bf16x8*)&lV[cur][m][c * 16 + l15][q4 * 8]
                            : *(const bf16x8*)&lOnes[l15][q4 * 8];
        o[c] = __builtin_amdgcn_mfma_f32_16x16x32_bf16(af.v, bv, o[c], 0, 0, 0);
      }
    }
    __syncthreads();
  }

#pragma unroll
  for (int rr = 0; rr < 4; ++rr) {
    float l = __shfl(o[4][rr], lane & 48, 64);  // col 0 of this quad
    const float inv = (l > 0.f) ? 1.0f / l : 0.f;
    const size_t row = base + qs + wid * 16 + q4 * 4 + rr;
#pragma unroll
    for (int c = 0; c < 4; ++c)
      out[row * 64 + c * 16 + l15] = o[c][rr] * inv;
  }
}

extern "C" void kernel_launch(void* const* d_in, const int* in_sizes, int n_in,
                              void* d_out, int out_size, void* d_ws, size_t ws_size,
                              hipStream_t stream) {
  const float* X  = (const float*)d_in[0];
  const float* Wq = (const float*)d_in[1];
  const float* bq = (const float*)d_in[2];
  const float* Wk = (const float*)d_in[3];
  const float* bk = (const float*)d_in[4];
  const float* Wv = (const float*)d_in[5];
  const float* bv = (const float*)d_in[6];
  const int* pad  = (const int*)d_in[8];
  float* out = (float*)d_out;

  short* Qg = (short*)d_ws;              // 4 MB
  short* Kg = Qg + 32768 * 64;           // 4 MB
  short* Vt = Kg + 32768 * 64;           // 4 MB, [32][64][1024]
  short* Wt = Vt + 32768 * 64;           // 288 KB (staged order)
  float* padneg = (float*)(Wt + 147456); // 128 KB

  wt_kernel<<<576, 256, 0, stream>>>(Wq, Wk, Wv, pad, Wt, padneg);
  proj_kernel<<<512, 256, 0, stream>>>(X, bq, bk, bv, Wt, Qg, Kg, Vt);
  attn_kernel<<<dim3(32, 16), 256, 0, stream>>>(Qg, Kg, Vt, padneg, out);
}